// Round 6
// baseline (30358.218 us; speedup 1.0000x reference)
//
#include <hip/hip_runtime.h>
#include <hip/hip_bf16.h>
#include <math.h>

// Sizes
#define BB 256
#define SS 64
#define EE 300
#define VV 30000
#define HH 512
#define H2 1024
#define DA 350
#define RR 8
#define CC 150
#define PP 16
#define CP 2400

// Output layout (elements, FLOAT32 — outputs are fp32, not bf16!)
#define ATT_OFF    0L
#define CL_OFF     131072L
#define PRED_OFF   169472L
#define ROUTES_OFF 5084672L

static __device__ __forceinline__ float sigmR6(float x) { return 1.0f / (1.0f + expf(-x)); }

// ---------------------------------------------------------------------------
// LSTM z: one thread per (dir,b,j). z = bias + x@Wih^T[j] + h_prev@Whh^T[j]
// hseq layout: [dir][s][b][u]
// ---------------------------------------------------------------------------
__global__ __launch_bounds__(256) void z_stepR6(
    const int* __restrict__ ids, const float* __restrict__ emb,
    const float* __restrict__ wihF, const float* __restrict__ whhF,
    const float* __restrict__ bihF, const float* __restrict__ bhhF,
    const float* __restrict__ wihB, const float* __restrict__ whhB,
    const float* __restrict__ bihB, const float* __restrict__ bhhB,
    const float* __restrict__ hseq, float* __restrict__ zbuf, int step)
{
    const int idx = blockIdx.x * 256 + threadIdx.x;
    if (idx >= 2 * BB * 2048) return;
    const int dir = idx >> 19;
    const int rem = idx & 524287;
    const int b = rem >> 11, j = rem & 2047;
    const int s = dir ? (SS - 1 - step) : step;
    int tok = ids[(long)b * SS + s];
    if ((unsigned)tok >= (unsigned)VV) tok = 0;
    float z = dir ? (bihB[j] + bhhB[j]) : (bihF[j] + bhhF[j]);
    {
        const float* er = emb + (long)tok * EE;
        const float* wr = (dir ? wihB : wihF) + (long)j * EE;
        for (int e = 0; e < EE; ++e) z = fmaf(er[e], wr[e], z);
    }
    if (step > 0) {
        const int sp = dir ? (s + 1) : (s - 1);
        const float* hr = hseq + (((long)dir * SS + sp) * BB + b) * HH;
        const float* vr = (dir ? whhB : whhF) + (long)j * HH;
        for (int u = 0; u < HH; ++u) z = fmaf(hr[u], vr[u], z);
    }
    zbuf[idx] = z;
}

__global__ __launch_bounds__(256) void gatesR6(
    const float* __restrict__ zbuf, float* __restrict__ cbuf,
    float* __restrict__ hseq, int step)
{
    const int idx = blockIdx.x * 256 + threadIdx.x;
    if (idx >= 2 * BB * HH) return;
    const int dir = idx >> 17;
    const int rem = idx & 131071;
    const int b = rem >> 9, u = rem & 511;
    const float* z = zbuf + ((long)dir * BB + b) * 2048;
    const float zi = z[u], zf = z[HH + u], zg = z[2 * HH + u], zo = z[3 * HH + u];
    float* cp = cbuf + ((long)dir * BB + b) * HH + u;
    float c = (step > 0) ? *cp : 0.0f;
    c = sigmR6(zf) * c + sigmR6(zi) * tanhf(zg);
    *cp = c;
    const int s = dir ? (SS - 1 - step) : step;
    hseq[(((long)dir * SS + s) * BB + b) * HH + u] = sigmR6(zo) * tanhf(c);
}

// pre[b,s,a] = tanh(sum_d out(b,s,d) * ws1[a,d])
__global__ __launch_bounds__(256) void preR6(
    const float* __restrict__ hseq, const float* __restrict__ ws1,
    float* __restrict__ pre)
{
    const long idx = (long)blockIdx.x * 256 + threadIdx.x;
    if (idx >= (long)BB * SS * DA) return;
    const int a = (int)(idx % DA);
    const int row = (int)(idx / DA);
    const int b = row >> 6, s = row & 63;
    const float* w = ws1 + (long)a * H2;
    const float* h0 = hseq + (((long)0 * SS + s) * BB + b) * HH;
    const float* h1 = hseq + (((long)1 * SS + s) * BB + b) * HH;
    float acc = 0.0f;
    for (int d = 0; d < HH; ++d) acc = fmaf(h0[d], w[d], acc);
    for (int d = 0; d < HH; ++d) acc = fmaf(h1[d], w[HH + d], acc);
    pre[idx] = tanhf(acc);
}

// attlog[b,r,s] = sum_a pre[b,s,a] * ws2[r,a]
__global__ __launch_bounds__(256) void attlogR6(
    const float* __restrict__ pre, const float* __restrict__ ws2,
    float* __restrict__ attlog)
{
    const int idx = blockIdx.x * 256 + threadIdx.x;
    if (idx >= BB * RR * SS) return;
    const int s = idx & 63, r = (idx >> 6) & 7, b = idx >> 9;
    const float* p = pre + ((long)b * SS + s) * DA;
    const float* w = ws2 + (long)r * DA;
    float acc = 0.0f;
    for (int a = 0; a < DA; ++a) acc = fmaf(p[a], w[a], acc);
    attlog[idx] = acc;
}

// softmax over s per (b,r) -> fp32 attention output
__global__ __launch_bounds__(256) void softR6(
    const float* __restrict__ attlog, float* __restrict__ att_out)
{
    const int idx = blockIdx.x * 256 + threadIdx.x;
    if (idx >= BB * RR) return;
    const float* L = attlog + (long)idx * SS;
    float mx = L[0];
    for (int s = 1; s < SS; ++s) mx = fmaxf(mx, L[s]);
    float sm = 0.0f;
    for (int s = 0; s < SS; ++s) sm += expf(L[s] - mx);
    for (int s = 0; s < SS; ++s)
        att_out[(long)idx * SS + s] = expf(L[s] - mx) / sm;
}

// sem[b,r,d] = sum_s att[b,r,s] * out(b,s,d)   (att read from d_out, fp32)
__global__ __launch_bounds__(256) void semR6(
    const float* __restrict__ att, const float* __restrict__ hseq,
    float* __restrict__ sem)
{
    const long idx = (long)blockIdx.x * 256 + threadIdx.x;
    if (idx >= (long)BB * RR * H2) return;
    const int d = (int)(idx & 1023);
    const int r = (int)((idx >> 10) & 7);
    const int b = (int)(idx >> 13);
    const int dir = d >> 9, u = d & 511;
    const float* aw = att + ((long)b * RR + r) * SS;
    float acc = 0.0f;
    for (int s = 0; s < SS; ++s)
        acc = fmaf(aw[s], hseq[(((long)dir * SS + s) * BB + b) * HH + u], acc);
    sem[idx] = acc;
}

// pred[b,r,k] = sum_d sem[b,r,d] * caps[r,d,k]  -> fp32 straight into d_out
__global__ __launch_bounds__(256) void predR6(
    const float* __restrict__ sem, const float* __restrict__ caps,
    float* __restrict__ pred_out)
{
    const long idx = (long)blockIdx.x * 256 + threadIdx.x;
    if (idx >= (long)BB * RR * CP) return;
    const int k = (int)(idx % CP);
    const int row = (int)(idx / CP);
    const int r = row & 7;
    const float* sv = sem + (long)row * H2;
    const float* w = caps + (long)r * H2 * CP + k;
    float acc = 0.0f;
    for (int d = 0; d < H2; ++d) acc = fmaf(sv[d], w[(long)d * CP], acc);
    pred_out[idx] = acc;
}

// ---------------------------------------------------------------------------
// Dynamic routing: reads pred from d_out (fp32), writes cls + routes (fp32)
// ---------------------------------------------------------------------------
__global__ __launch_bounds__(256) void routeR6(
    const float* __restrict__ pred,
    float* __restrict__ cls_out, float* __restrict__ routes_out)
{
    __shared__ float predS[RR * CP];
    __shared__ float logitS[RR * CC];
    __shared__ float routeS[RR * CC];
    __shared__ float preactS[CP];
    __shared__ float vS[CP];
    __shared__ float scaleS[CC];
    __shared__ float rmax[RR], rsum[RR];
    const int b = blockIdx.x, tid = threadIdx.x;
    const float* ps = pred + (long)b * RR * CP;
    for (int i = tid; i < RR * CP; i += 256) predS[i] = ps[i];
    for (int i = tid; i < RR * CC; i += 256) logitS[i] = 0.0f;
    __syncthreads();

    for (int it = 0; it < 3; ++it) {
        if (tid < RR) {
            float mx = -1e30f;
            for (int c = 0; c < CC; ++c) mx = fmaxf(mx, logitS[tid * CC + c]);
            float sm = 0.0f;
            for (int c = 0; c < CC; ++c) sm += expf(logitS[tid * CC + c] - mx);
            rmax[tid] = mx; rsum[tid] = sm;
        }
        __syncthreads();
        for (int i = tid; i < RR * CC; i += 256) {
            const int r = i / CC;
            routeS[i] = expf(logitS[i] - rmax[r]) / rsum[r];
        }
        __syncthreads();
        for (int cp = tid; cp < CP; cp += 256) {
            const int c = cp >> 4;
            float a = 0.0f;
            #pragma unroll
            for (int r = 0; r < RR; ++r)
                a = fmaf(routeS[r * CC + c], predS[r * CP + cp], a);
            preactS[cp] = a;
        }
        __syncthreads();
        for (int c = tid; c < CC; c += 256) {
            float n2 = 0.0f;
            #pragma unroll
            for (int p = 0; p < PP; ++p) { const float x = preactS[c * PP + p]; n2 = fmaf(x, x, n2); }
            scaleS[c] = (n2 / (1.0f + n2)) / sqrtf(n2 + 1e-9f);
        }
        __syncthreads();
        for (int cp = tid; cp < CP; cp += 256) vS[cp] = preactS[cp] * scaleS[cp >> 4];
        __syncthreads();
        for (int i = tid; i < RR * CC; i += 256) {
            const int r = i / CC, c = i % CC;
            float a = 0.0f;
            #pragma unroll
            for (int p = 0; p < PP; ++p)
                a = fmaf(predS[r * CP + c * PP + p], vS[c * PP + p], a);
            logitS[i] += a;
        }
        __syncthreads();
    }

    for (int i = tid; i < RR * CC; i += 256)
        routes_out[(long)b * RR * CC + i] = routeS[i];
    for (int c = tid; c < CC; c += 256) {
        float n2 = 0.0f;
        #pragma unroll
        for (int p = 0; p < PP; ++p) { const float x = vS[c * PP + p]; n2 = fmaf(x, x, n2); }
        cls_out[(long)b * CC + c] = sqrtf(n2);
    }
}

// ---------------------------------------------------------------------------
extern "C" void kernel_launch(void* const* d_in, const int* in_sizes, int n_in,
                              void* d_out, int out_size, void* d_ws, size_t ws_size,
                              hipStream_t stream)
{
    (void)in_sizes; (void)n_in; (void)out_size;
    const int*   ids   = (const int*)d_in[0];
    const float* emb   = (const float*)d_in[2];
    const float* wih_f = (const float*)d_in[3];
    const float* whh_f = (const float*)d_in[4];
    const float* bih_f = (const float*)d_in[5];
    const float* bhh_f = (const float*)d_in[6];
    const float* wih_b = (const float*)d_in[7];
    const float* whh_b = (const float*)d_in[8];
    const float* bih_b = (const float*)d_in[9];
    const float* bhh_b = (const float*)d_in[10];
    const float* ws1   = (const float*)d_in[11];
    const float* ws2   = (const float*)d_in[12];
    const float* caps  = (const float*)d_in[13];
    float* out = (float*)d_out;   // fp32 outputs

    float* ws = (float*)d_ws;
    float* hseq = ws;                        // 16,777,216  [dir][s][b][u]
    float* zbuf = hseq + 16777216;           //  1,048,576
    float* cbuf = zbuf + 1048576;            //    262,144
    float* pre  = cbuf + 262144;             //  5,734,400
    float* sem  = pre + 5734400;             //  2,097,152
    float* attlog = zbuf;                    // alias (zbuf dead after LSTM)
    const size_t need = (size_t)(16777216 + 1048576 + 262144 + 5734400 + 2097152) * 4;
    if (ws_size < need) return;   // would show as error == 1.72e-2 (all-zero out)

    for (int step = 0; step < SS; ++step) {
        z_stepR6<<<4096, 256, 0, stream>>>(ids, emb, wih_f, whh_f, bih_f, bhh_f,
                                           wih_b, whh_b, bih_b, bhh_b,
                                           hseq, zbuf, step);
        gatesR6<<<1024, 256, 0, stream>>>(zbuf, cbuf, hseq, step);
    }

    preR6<<<22400, 256, 0, stream>>>(hseq, ws1, pre);
    attlogR6<<<512, 256, 0, stream>>>(pre, ws2, attlog);
    softR6<<<8, 256, 0, stream>>>(attlog, out + ATT_OFF);
    semR6<<<8192, 256, 0, stream>>>(out + ATT_OFF, hseq, sem);
    predR6<<<19200, 256, 0, stream>>>(sem, caps, out + PRED_OFF);
    routeR6<<<BB, 256, 0, stream>>>(out + PRED_OFF, out + CL_OFF, out + ROUTES_OFF);
}

// Round 7
// 3474.717 us; speedup vs baseline: 8.7369x; 8.7369x over previous
//
#include <hip/hip_runtime.h>
#include <hip/hip_bf16.h>
#include <math.h>

// Sizes
#define BB 256
#define SS 64
#define EE 300
#define EP 304   // padded embed
#define KK9 816  // EP + HH (concat K for fused LSTM gemm)
#define VV 30000
#define HH 512
#define H2 1024
#define DA 350
#define RR 8
#define CC 150
#define PP 16
#define CP 2400

// Output layout (elements, fp32)
#define ATT_OFF    0L
#define CL_OFF     131072L
#define PRED_OFF   169472L
#define ROUTES_OFF 5084672L

static __device__ __forceinline__ float sigm7(float x) { return 1.0f / (1.0f + expf(-x)); }

// ---------------------------------------------------------------------------
// X[s][b][EP] = embedding[ids[b][s]][:], zero-padded cols 300..303
// ---------------------------------------------------------------------------
__global__ __launch_bounds__(256) void k_gather7(
    const int* __restrict__ ids, const float* __restrict__ emb, float* __restrict__ X)
{
    const long idx = (long)blockIdx.x * 256 + threadIdx.x;
    if (idx >= (long)SS * BB * EP) return;
    const int row = (int)(idx / EP), e = (int)(idx % EP);
    const int s = row >> 8, b = row & 255;
    int tok = ids[(long)b * SS + s];
    if ((unsigned)tok >= (unsigned)VV) tok = 0;
    X[idx] = (e < EE) ? emb[(long)tok * EE + e] : 0.0f;
}

// Wp[dir][2048][816]: cols 0..299 = wih, 300..303 = 0, 304..815 = whh
__global__ __launch_bounds__(256) void k_packw7(
    const float* __restrict__ wihF, const float* __restrict__ whhF,
    const float* __restrict__ wihB, const float* __restrict__ whhB,
    float* __restrict__ Wp)
{
    const long idx = (long)blockIdx.x * 256 + threadIdx.x;
    if (idx >= (long)2 * 2048 * KK9) return;
    const int dir = (int)(idx / (2048 * KK9));
    const int rem = (int)(idx % (2048 * KK9));
    const int j = rem / KK9, k = rem % KK9;
    const float* wih = dir ? wihB : wihF;
    const float* whh = dir ? whhB : whhF;
    float v;
    if (k < EE)       v = wih[(long)j * EE + k];
    else if (k < EP)  v = 0.0f;
    else              v = whh[(long)j * HH + (k - EP)];
    Wp[idx] = v;
}

// ---------------------------------------------------------------------------
// Fused LSTM step GEMM: z[dir][b][j] = sum_k A(b,k) * Wp[dir][j][k]
// A(b, k<304) = X[s_eff][b][k];  A(b, k>=304) = hs[b][s_prev][dir*512 + k-304]
// 64x64 tile, BK=16; K-tiles 0..18 from X, 19..50 from hs (step>0 only).
// grid (32, 4, 2), 256 thr.
// ---------------------------------------------------------------------------
__global__ __launch_bounds__(256) void k_lstm_gemm7(
    const float* __restrict__ X, const float* __restrict__ hs,
    const float* __restrict__ Wp, float* __restrict__ zbuf, int step)
{
    __shared__ float As[16][68];
    __shared__ float Bs[16][68];
    const int dir = blockIdx.z;
    const int n0 = blockIdx.x * 64;
    const int m0 = blockIdx.y * 64;
    const int s_eff  = dir ? (SS - 1 - step) : step;
    const int s_prev = dir ? (s_eff + 1) : (s_eff - 1);
    const float* Xs = X + (long)s_eff * BB * EP;
    const float* W  = Wp + (long)dir * 2048 * KK9;
    const int tid = threadIdx.x;
    const int ty = tid >> 4, tx = tid & 15;
    float acc[4][4] = {};

    const int KT = (step == 0) ? 19 : 51;
    for (int t = 0; t < KT; ++t) {
        const int k0 = t * 16;
        {
            const int i = tid >> 2, kk = (tid & 3) * 4;
            const int row = m0 + i;
            float4 v;
            if (t < 19)
                v = *(const float4*)(Xs + (long)row * EP + k0 + kk);
            else
                v = *(const float4*)(hs + ((long)row * SS + s_prev) * H2
                                      + dir * HH + (k0 - EP) + kk);
            As[kk][i] = v.x; As[kk + 1][i] = v.y; As[kk + 2][i] = v.z; As[kk + 3][i] = v.w;
        }
        {
            const int j = tid >> 2, kk = (tid & 3) * 4;
            const float4 v = *(const float4*)(W + (long)(n0 + j) * KK9 + k0 + kk);
            Bs[kk][j] = v.x; Bs[kk + 1][j] = v.y; Bs[kk + 2][j] = v.z; Bs[kk + 3][j] = v.w;
        }
        __syncthreads();
        #pragma unroll
        for (int k = 0; k < 16; ++k) {
            const float4 av = *(const float4*)&As[k][ty * 4];
            const float4 bv = *(const float4*)&Bs[k][tx * 4];
            const float a4[4] = {av.x, av.y, av.z, av.w};
            const float b4[4] = {bv.x, bv.y, bv.z, bv.w};
            #pragma unroll
            for (int i = 0; i < 4; ++i)
                #pragma unroll
                for (int j = 0; j < 4; ++j)
                    acc[i][j] = fmaf(a4[i], b4[j], acc[i][j]);
        }
        __syncthreads();
    }

    float* C = zbuf + (long)dir * BB * 2048;
    #pragma unroll
    for (int i = 0; i < 4; ++i)
        #pragma unroll
        for (int j = 0; j < 4; ++j)
            C[(long)(m0 + ty * 4 + i) * 2048 + n0 + tx * 4 + j] = acc[i][j];
}

// ---------------------------------------------------------------------------
// Gates: add biases, update c, write h into hs[b][s_eff][dir*512+u]
// ---------------------------------------------------------------------------
__global__ __launch_bounds__(256) void k_gates7(
    const float* __restrict__ zbuf,
    const float* __restrict__ bihF, const float* __restrict__ bhhF,
    const float* __restrict__ bihB, const float* __restrict__ bhhB,
    float* __restrict__ cbuf, float* __restrict__ hs, int step)
{
    const int idx = blockIdx.x * 256 + threadIdx.x;
    if (idx >= 2 * BB * HH) return;
    const int dir = idx >> 17;
    const int rem = idx & 131071;
    const int b = rem >> 9, u = rem & 511;
    const float* z = zbuf + ((long)dir * BB + b) * 2048;
    const float* bi = dir ? bihB : bihF;
    const float* bh = dir ? bhhB : bhhF;
    const float zi = z[u]          + bi[u]          + bh[u];
    const float zf = z[HH + u]     + bi[HH + u]     + bh[HH + u];
    const float zg = z[2*HH + u]   + bi[2*HH + u]   + bh[2*HH + u];
    const float zo = z[3*HH + u]   + bi[3*HH + u]   + bh[3*HH + u];
    float* cp = cbuf + ((long)dir * BB + b) * HH + u;
    float c = (step > 0) ? *cp : 0.0f;
    c = sigm7(zf) * c + sigm7(zi) * tanhf(zg);
    *cp = c;
    const int s = dir ? (SS - 1 - step) : step;
    hs[((long)b * SS + s) * H2 + dir * HH + u] = sigm7(zo) * tanhf(c);
}

// ---------------------------------------------------------------------------
// Generic fp32 tiled GEMM (from round 1; validated infrastructure).
// BT=1: B as [N][K]; BT=0: B as [K][N]. ACT=1: tanh epilogue.
// ---------------------------------------------------------------------------
template<int BT, int ACT>
__global__ __launch_bounds__(256) void k_gemm7(
    const float* __restrict__ A, long lda, long sAz,
    const float* __restrict__ Bm, long ldb, long sBz,
    float* __restrict__ Cf, long ldc, long sCz, int N, int K)
{
    __shared__ float As[16][68];
    __shared__ float Bs[16][68];
    const int n0 = blockIdx.x * 64;
    const int m0 = blockIdx.y * 64;
    const float* Ab = A + (long)blockIdx.z * sAz;
    const float* Bb = Bm + (long)blockIdx.z * sBz;
    const int tid = threadIdx.x;
    const int ty = tid >> 4, tx = tid & 15;
    float acc[4][4] = {};

    for (int k0 = 0; k0 < K; k0 += 16) {
        {
            const int i = tid >> 2, kk = (tid & 3) * 4;
            const float4 v = *(const float4*)(Ab + (long)(m0 + i) * lda + k0 + kk);
            As[kk][i] = v.x; As[kk + 1][i] = v.y; As[kk + 2][i] = v.z; As[kk + 3][i] = v.w;
        }
        if (BT) {
            const int j = tid >> 2, kk = (tid & 3) * 4;
            const int n = n0 + j;
            float4 v = make_float4(0.f, 0.f, 0.f, 0.f);
            if (n < N) v = *(const float4*)(Bb + (long)n * ldb + k0 + kk);
            Bs[kk][j] = v.x; Bs[kk + 1][j] = v.y; Bs[kk + 2][j] = v.z; Bs[kk + 3][j] = v.w;
        } else {
            const int kk = tid >> 4, jj = (tid & 15) * 4;
            const int n = n0 + jj;
            float4 v = make_float4(0.f, 0.f, 0.f, 0.f);
            if (n + 3 < N) {
                v = *(const float4*)(Bb + (long)(k0 + kk) * ldb + n);
            } else {
                const float* src = Bb + (long)(k0 + kk) * ldb + n;
                if (n < N)     v.x = src[0];
                if (n + 1 < N) v.y = src[1];
                if (n + 2 < N) v.z = src[2];
            }
            *(float4*)&Bs[kk][jj] = v;
        }
        __syncthreads();
        #pragma unroll
        for (int k = 0; k < 16; ++k) {
            const float4 av = *(const float4*)&As[k][ty * 4];
            const float4 bv = *(const float4*)&Bs[k][tx * 4];
            const float a4[4] = {av.x, av.y, av.z, av.w};
            const float b4[4] = {bv.x, bv.y, bv.z, bv.w};
            #pragma unroll
            for (int i = 0; i < 4; ++i)
                #pragma unroll
                for (int j = 0; j < 4; ++j)
                    acc[i][j] = fmaf(a4[i], b4[j], acc[i][j]);
        }
        __syncthreads();
    }

    const long zc = (long)blockIdx.z * sCz;
    #pragma unroll
    for (int i = 0; i < 4; ++i) {
        const int m = m0 + ty * 4 + i;
        #pragma unroll
        for (int j = 0; j < 4; ++j) {
            const int n = n0 + tx * 4 + j;
            if (n < N) {
                float val = acc[i][j];
                if (ACT == 1) val = tanhf(val);
                Cf[zc + (long)m * ldc + n] = val;
            }
        }
    }
}

// attlog[b,r,s] = sum_a pre[b,s,a] * ws2[r,a]
__global__ __launch_bounds__(256) void attlog7(
    const float* __restrict__ pre, const float* __restrict__ ws2,
    float* __restrict__ attlog)
{
    const int idx = blockIdx.x * 256 + threadIdx.x;
    if (idx >= BB * RR * SS) return;
    const int s = idx & 63, r = (idx >> 6) & 7, b = idx >> 9;
    const float* p = pre + ((long)b * SS + s) * DA;
    const float* w = ws2 + (long)r * DA;
    float acc = 0.0f;
    for (int a = 0; a < DA; ++a) acc = fmaf(p[a], w[a], acc);
    attlog[idx] = acc;
}

// softmax over s per (b,r) -> fp32 attention output
__global__ __launch_bounds__(256) void soft7(
    const float* __restrict__ attlog, float* __restrict__ att_out)
{
    const int idx = blockIdx.x * 256 + threadIdx.x;
    if (idx >= BB * RR) return;
    const float* L = attlog + (long)idx * SS;
    float mx = L[0];
    for (int s = 1; s < SS; ++s) mx = fmaxf(mx, L[s]);
    float sm = 0.0f;
    for (int s = 0; s < SS; ++s) sm += expf(L[s] - mx);
    for (int s = 0; s < SS; ++s)
        att_out[(long)idx * SS + s] = expf(L[s] - mx) / sm;
}

// sem[b,r,d] = sum_s att[b,r,s] * hs[b][s][d]
__global__ __launch_bounds__(256) void sem7(
    const float* __restrict__ att, const float* __restrict__ hs,
    float* __restrict__ sem)
{
    const long idx = (long)blockIdx.x * 256 + threadIdx.x;
    if (idx >= (long)BB * RR * H2) return;
    const int d = (int)(idx & 1023);
    const int r = (int)((idx >> 10) & 7);
    const int b = (int)(idx >> 13);
    const float* aw = att + ((long)b * RR + r) * SS;
    float acc = 0.0f;
    for (int s = 0; s < SS; ++s)
        acc = fmaf(aw[s], hs[((long)b * SS + s) * H2 + d], acc);
    sem[idx] = acc;
}

// ---------------------------------------------------------------------------
// Dynamic routing: reads pred (fp32, in d_out), writes cls + routes (fp32)
// ---------------------------------------------------------------------------
__global__ __launch_bounds__(256) void route7(
    const float* __restrict__ pred,
    float* __restrict__ cls_out, float* __restrict__ routes_out)
{
    __shared__ float predS[RR * CP];
    __shared__ float logitS[RR * CC];
    __shared__ float routeS[RR * CC];
    __shared__ float preactS[CP];
    __shared__ float vS[CP];
    __shared__ float scaleS[CC];
    __shared__ float rmax[RR], rsum[RR];
    const int b = blockIdx.x, tid = threadIdx.x;
    const float* ps = pred + (long)b * RR * CP;
    for (int i = tid; i < RR * CP; i += 256) predS[i] = ps[i];
    for (int i = tid; i < RR * CC; i += 256) logitS[i] = 0.0f;
    __syncthreads();

    for (int it = 0; it < 3; ++it) {
        if (tid < RR) {
            float mx = -1e30f;
            for (int c = 0; c < CC; ++c) mx = fmaxf(mx, logitS[tid * CC + c]);
            float sm = 0.0f;
            for (int c = 0; c < CC; ++c) sm += expf(logitS[tid * CC + c] - mx);
            rmax[tid] = mx; rsum[tid] = sm;
        }
        __syncthreads();
        for (int i = tid; i < RR * CC; i += 256) {
            const int r = i / CC;
            routeS[i] = expf(logitS[i] - rmax[r]) / rsum[r];
        }
        __syncthreads();
        for (int cp = tid; cp < CP; cp += 256) {
            const int c = cp >> 4;
            float a = 0.0f;
            #pragma unroll
            for (int r = 0; r < RR; ++r)
                a = fmaf(routeS[r * CC + c], predS[r * CP + cp], a);
            preactS[cp] = a;
        }
        __syncthreads();
        for (int c = tid; c < CC; c += 256) {
            float n2 = 0.0f;
            #pragma unroll
            for (int p = 0; p < PP; ++p) { const float x = preactS[c * PP + p]; n2 = fmaf(x, x, n2); }
            scaleS[c] = (n2 / (1.0f + n2)) / sqrtf(n2 + 1e-9f);
        }
        __syncthreads();
        for (int cp = tid; cp < CP; cp += 256) vS[cp] = preactS[cp] * scaleS[cp >> 4];
        __syncthreads();
        for (int i = tid; i < RR * CC; i += 256) {
            const int r = i / CC, c = i % CC;
            float a = 0.0f;
            #pragma unroll
            for (int p = 0; p < PP; ++p)
                a = fmaf(predS[r * CP + c * PP + p], vS[c * PP + p], a);
            logitS[i] += a;
        }
        __syncthreads();
    }

    for (int i = tid; i < RR * CC; i += 256)
        routes_out[(long)b * RR * CC + i] = routeS[i];
    for (int c = tid; c < CC; c += 256) {
        float n2 = 0.0f;
        #pragma unroll
        for (int p = 0; p < PP; ++p) { const float x = vS[c * PP + p]; n2 = fmaf(x, x, n2); }
        cls_out[(long)b * CC + c] = sqrtf(n2);
    }
}

// ---------------------------------------------------------------------------
extern "C" void kernel_launch(void* const* d_in, const int* in_sizes, int n_in,
                              void* d_out, int out_size, void* d_ws, size_t ws_size,
                              hipStream_t stream)
{
    (void)in_sizes; (void)n_in; (void)out_size;
    const int*   ids   = (const int*)d_in[0];
    const float* emb   = (const float*)d_in[2];
    const float* wih_f = (const float*)d_in[3];
    const float* whh_f = (const float*)d_in[4];
    const float* bih_f = (const float*)d_in[5];
    const float* bhh_f = (const float*)d_in[6];
    const float* wih_b = (const float*)d_in[7];
    const float* whh_b = (const float*)d_in[8];
    const float* bih_b = (const float*)d_in[9];
    const float* bhh_b = (const float*)d_in[10];
    const float* ws1   = (const float*)d_in[11];
    const float* ws2   = (const float*)d_in[12];
    const float* caps  = (const float*)d_in[13];
    float* out = (float*)d_out;   // fp32 outputs

    // Workspace: hs | zbuf | cbuf | region1(X+Wp -> pre+sem) ; attlog aliases zbuf
    float* ws   = (float*)d_ws;
    float* hs   = ws;                         // [256][64][1024] = 16,777,216
    float* zbuf = hs + 16777216;              // [2][256][2048]  =  1,048,576
    float* cbuf = zbuf + 1048576;             // [2][256][512]   =    262,144
    float* region1 = cbuf + 262144;           // 8,323,072
    float* X    = region1;                    // [64][256][304]  =  4,980,736
    float* Wp   = region1 + 4980736;          // [2][2048][816]  =  3,342,336
    float* pre  = region1;                    // [256][64][350]  =  5,734,400 (after LSTM)
    float* sem  = region1 + 5734400;          // [256][8][1024]  =  2,097,152
    float* attlog = zbuf;                     //    131,072 (zbuf dead after LSTM)
    const size_t need = (size_t)(16777216 + 1048576 + 262144 + 8323072) * 4;
    if (ws_size < need) return;

    // Stage inputs
    k_gather7<<<(int)(((long)SS * BB * EP + 255) / 256), 256, 0, stream>>>(ids, emb, X);
    k_packw7<<<(int)(((long)2 * 2048 * KK9 + 255) / 256), 256, 0, stream>>>(
        wih_f, whh_f, wih_b, whh_b, Wp);

    // Bidirectional LSTM: one fused GEMM + gates per step
    for (int step = 0; step < SS; ++step) {
        k_lstm_gemm7<<<dim3(32, 4, 2), 256, 0, stream>>>(X, hs, Wp, zbuf, step);
        k_gates7<<<1024, 256, 0, stream>>>(zbuf, bih_f, bhh_f, bih_b, bhh_b,
                                           cbuf, hs, step);
    }

    // pre = tanh(hs @ ws1^T)  [M=16384, N=350, K=1024]
    {
        dim3 g((DA + 63) / 64, (BB * SS) / 64, 1);
        k_gemm7<1, 1><<<g, 256, 0, stream>>>(hs, H2, 0, ws1, H2, 0,
                                             pre, DA, 0, DA, H2);
    }

    attlog7<<<512, 256, 0, stream>>>(pre, ws2, attlog);
    soft7<<<8, 256, 0, stream>>>(attlog, out + ATT_OFF);
    sem7<<<8192, 256, 0, stream>>>(out + ATT_OFF, hs, sem);

    // pred[b,r,:] = sem[b,r,:] @ caps[r]  [M=256, N=2400, K=1024] x8 (z=r)
    {
        dim3 g((CP + 63) / 64, BB / 64, RR);
        k_gemm7<0, 0><<<g, 256, 0, stream>>>(sem, (long)RR * H2, H2,
                                             caps, CP, (long)H2 * CP,
                                             out + PRED_OFF, (long)RR * CP, CP, CP, H2);
    }

    route7<<<BB, 256, 0, stream>>>(out + PRED_OFF, out + CL_OFF, out + ROUTES_OFF);
}